// Round 2
// baseline (175.339 us; speedup 1.0000x reference)
//
#include <hip/hip_runtime.h>

#define NUM_BINS 15

// Kernel 1: one 64-lane wave per row. Computes confidence = 1/sum(exp(l - max)),
// prediction = argmax(logits), bins into 15 confidence bins, accumulates
// per-block in LDS, flushes to global workspace with atomics.
__global__ __launch_bounds__(256) void ece_main_kernel(
    const float* __restrict__ logits,
    const int* __restrict__ targs,
    double* __restrict__ g_conf,      // [NUM_BINS]
    unsigned int* __restrict__ g_cnt, // [NUM_BINS]
    unsigned int* __restrict__ g_acc, // [NUM_BINS]
    int N)
{
    __shared__ float s_conf[NUM_BINS];
    __shared__ unsigned int s_cnt[NUM_BINS];
    __shared__ unsigned int s_acc[NUM_BINS];

    const int tid = threadIdx.x;
    if (tid < NUM_BINS) { s_conf[tid] = 0.0f; s_cnt[tid] = 0u; s_acc[tid] = 0u; }
    __syncthreads();

    const int lane = tid & 63;
    const int waveInBlock = tid >> 6;
    const int wavesPerBlock = blockDim.x >> 6;
    const int globalWave = blockIdx.x * wavesPerBlock + waveInBlock;
    const int numWaves = gridDim.x * wavesPerBlock;

    for (int row = globalWave; row < N; row += numWaves) {
        // C = 200 floats = 50 float4; lanes 0..49 each load one float4 (16B, aligned: 800B row stride)
        const float4* rp = reinterpret_cast<const float4*>(logits + (size_t)row * 200);
        float v0 = -INFINITY, v1 = -INFINITY, v2 = -INFINITY, v3 = -INFINITY;
        if (lane < 50) {
            float4 v = rp[lane];
            v0 = v.x; v1 = v.y; v2 = v.z; v3 = v.w;
        }

        // per-lane max + argmax, first occurrence wins (strictly-greater keeps earliest)
        float m = v0; int mi = 4 * lane;
        if (v1 > m) { m = v1; mi = 4 * lane + 1; }
        if (v2 > m) { m = v2; mi = 4 * lane + 2; }
        if (v3 > m) { m = v3; mi = 4 * lane + 3; }

        // 64-lane butterfly reduce: max value, ties -> smaller index (matches jnp.argmax)
        #pragma unroll
        for (int off = 32; off > 0; off >>= 1) {
            float om = __shfl_xor(m, off);
            int omi = __shfl_xor(mi, off);
            if (om > m || (om == m && omi < mi)) { m = om; mi = omi; }
        }

        // sum of exp(x - max); idle lanes have -inf -> exp contributes 0
        float s = __expf(v0 - m) + __expf(v1 - m) + __expf(v2 - m) + __expf(v3 - m);
        #pragma unroll
        for (int off = 32; off > 0; off >>= 1) s += __shfl_xor(s, off);

        if (lane == 0) {
            float conf = 1.0f / s;                       // = max softmax prob
            int b = (int)ceilf(conf * (float)NUM_BINS) - 1;
            b = min(max(b, 0), NUM_BINS - 1);
            atomicAdd(&s_conf[b], conf);
            atomicAdd(&s_cnt[b], 1u);
            if (mi == targs[row]) atomicAdd(&s_acc[b], 1u);
        }
    }

    __syncthreads();
    if (tid < NUM_BINS) {
        unsigned int c = s_cnt[tid];
        if (c > 0u) {
            atomicAdd(&g_cnt[tid], c);
            atomicAdd(&g_acc[tid], s_acc[tid]);
            atomicAdd(&g_conf[tid], (double)s_conf[tid]);
        }
    }
}

// Kernel 2: final reduction over the 15 bins -> ece scalar.
__global__ void ece_final_kernel(
    const double* __restrict__ g_conf,
    const unsigned int* __restrict__ g_cnt,
    const unsigned int* __restrict__ g_acc,
    float* __restrict__ out,
    int N)
{
    const int t = threadIdx.x;
    float part = 0.0f;
    if (t < NUM_BINS) {
        unsigned int c = g_cnt[t];
        if (c > 0u) {
            double dc = (double)c;
            double avg_conf = g_conf[t] / dc;
            double acc = (double)g_acc[t] / dc;
            double gap = fabs(avg_conf - acc);
            part = (float)(gap * (dc / (double)N));
        }
    }
    #pragma unroll
    for (int off = 32; off > 0; off >>= 1) part += __shfl_xor(part, off);
    if (t == 0) out[0] = part;
}

extern "C" void kernel_launch(void* const* d_in, const int* in_sizes, int n_in,
                              void* d_out, int out_size, void* d_ws, size_t ws_size,
                              hipStream_t stream) {
    const float* logits = (const float*)d_in[0];
    const int* targs = (const int*)d_in[1];   // jax int64 -> int32 (x64 disabled)
    const int N = in_sizes[1];                // 524288 rows

    // workspace layout: double conf[15] | u32 cnt[15] | u32 acc[15]
    double* g_conf = (double*)d_ws;
    unsigned int* g_cnt = (unsigned int*)(g_conf + NUM_BINS);
    unsigned int* g_acc = g_cnt + NUM_BINS;
    const size_t ws_used = NUM_BINS * (sizeof(double) + 2 * sizeof(unsigned int));

    hipMemsetAsync(d_ws, 0, ws_used, stream);

    const int block = 256;                     // 4 waves/block
    const int grid = 2048;                     // 8 blocks/CU on 256 CUs, grid-stride
    ece_main_kernel<<<grid, block, 0, stream>>>(logits, targs, g_conf, g_cnt, g_acc, N);
    ece_final_kernel<<<1, 64, 0, stream>>>(g_conf, g_cnt, g_acc, (float*)d_out, N);
}